// Round 1
// baseline (391.259 us; speedup 1.0000x reference)
//
#include <hip/hip_runtime.h>
#include <hip/hip_cooperative_groups.h>

namespace cg = cooperative_groups;

// Problem constants (fixed by setup_inputs): B=16, N=3000, M=300, L=80, K=4
#define BB 16
#define NN 3000
#define MM 300
#define LL 80
#define KK 4
#define IOU_THRESH 0.6f
#define GRID 512   // 2 blocks/CU on 256 CUs; co-residency guaranteed by __launch_bounds__(256,2)

typedef unsigned long long u64;

struct Box { float x1, y1, x2, y2, area; };

__device__ __forceinline__ Box to_xyxy(float4 b) {
#pragma clang fp contract(off)
    Box r;
    r.x1 = b.x - 0.5f * b.z;
    r.y1 = b.y - 0.5f * b.w;
    r.x2 = b.x + 0.5f * b.z;
    r.y2 = b.y + 0.5f * b.w;
    r.area = (r.x2 - r.x1) * (r.y2 - r.y1);
    return r;
}

// Must be bitwise-identical between top phase and asn phase (iou == gmax equality depends on it).
__device__ __forceinline__ float pair_iou(Box a, Box b) {
#pragma clang fp contract(off)
    float ltx = fmaxf(a.x1, b.x1);
    float lty = fmaxf(a.y1, b.y1);
    float rbx = fminf(a.x2, b.x2);
    float rby = fminf(a.y2, b.y2);
    float wx = fmaxf(rbx - ltx, 0.0f);
    float wy = fmaxf(rby - lty, 0.0f);
    float inter = wx * wy;
    float uni = a.area + b.area - inter;
    return inter / fmaxf(uni, 1e-9f);
}

// monotonic float <-> u32 (order-preserving bijection, finite values)
__device__ __forceinline__ unsigned int f32_to_ordered(float f) {
    unsigned int u = __float_as_uint(f);
    return (u & 0x80000000u) ? ~u : (u | 0x80000000u);
}
__device__ __forceinline__ float ordered_to_f32(unsigned int u) {
    unsigned int b = (u & 0x80000000u) ? (u & 0x7FFFFFFFu) : ~u;
    return __uint_as_float(b);
}

__device__ __forceinline__ u64 umax64(u64 a, u64 b) { return a > b ? a : b; }
__device__ __forceinline__ u64 umin64(u64 a, u64 b) { return a < b ? a : b; }

__device__ __forceinline__ u64 shfl_xor_u64(u64 v, int mask) {
    int lo = __shfl_xor((int)(unsigned)v, mask, 64);
    int hi = __shfl_xor((int)(unsigned)(v >> 32), mask, 64);
    return ((u64)(unsigned)hi << 32) | (u64)(unsigned)lo;
}

// branchless insert of k into sorted-desc 4-list
__device__ __forceinline__ void topins(u64 t[4], u64 k) {
    u64 c0 = umin64(t[0], k);
    t[0] = umax64(t[0], k);
    u64 c1 = umin64(t[1], c0);
    t[1] = umax64(t[1], c0);
    u64 c2 = umin64(t[2], c1);
    t[2] = umax64(t[2], c1);
    t[3] = umax64(t[3], c2);
}

// butterfly: top-4 of the union of all 64 lanes' sorted-desc 4-lists (all lanes get result)
__device__ __forceinline__ void wave_merge_top4(u64 t[4]) {
    #pragma unroll
    for (int s = 1; s < 64; s <<= 1) {
        u64 b0 = shfl_xor_u64(t[0], s);
        u64 b1 = shfl_xor_u64(t[1], s);
        u64 b2 = shfl_xor_u64(t[2], s);
        u64 b3 = shfl_xor_u64(t[3], s);
        u64 a0 = t[0], a1 = t[1], a2 = t[2], a3 = t[3];
        t[0] = umax64(a0, b0);
        t[1] = umax64(umin64(a0, b0), umax64(a1, b1));
        t[2] = umax64(umax64(a2, b2), umax64(umin64(a0, b1), umin64(a1, b0)));
        t[3] = umax64(umax64(a3, b3),
               umax64(umin64(a0, b2), umax64(umin64(a1, b1), umin64(a2, b0))));
    }
}

// ===========================================================================
// Fused cooperative kernel: bin -> sync -> top -> sync -> asn -> sync -> epilogue.
// Replaces 4 dependent dispatches (launch-overhead-bound at ~90us) with one
// dispatch + 3 grid syncs.
// d_out layout: floats [0,38400) GT records | [38400,57600) topv | [57600,76800) topi
// ===========================================================================
__global__ __launch_bounds__(256, 2) void kAll(
    const float4* __restrict__ props, const int* __restrict__ pinds,
    const int* __restrict__ glab, const float4* __restrict__ gbox,
    float* __restrict__ out, int* __restrict__ counts,
    int* __restrict__ pstart, int* __restrict__ pcnt,
    int* __restrict__ gstart, int* __restrict__ gcnt,
    unsigned short* __restrict__ pidx, unsigned short* __restrict__ gidx)
{
    cg::grid_group gg = cg::this_grid();
    __shared__ int hist[LL], cur[LL];
    const int tid = threadIdx.x;
    const int blk = blockIdx.x;

    // ---- Phase 0: label-bucket binning (blocks 0..15: proposals, 16..31: GT),
    //      counts zeroing on the rest. Bucket order nondeterministic (LDS atomic
    //      cursors) but downstream is order-invariant (u64 key max / OR / adds).
    if (blk < BB) {
        int b = blk;
        if (tid < LL) hist[tid] = 0;
        __syncthreads();
        for (int n = tid; n < NN; n += 256) atomicAdd(&hist[pinds[b * NN + n]], 1);
        __syncthreads();
        if (tid < LL) {
            int s = 0;
            for (int j = 0; j < tid; ++j) s += hist[j];
            cur[tid] = s; pstart[b * LL + tid] = s; pcnt[b * LL + tid] = hist[tid];
        }
        __syncthreads();
        for (int n = tid; n < NN; n += 256) {
            int l = pinds[b * NN + n];
            int pos = atomicAdd(&cur[l], 1);
            pidx[b * NN + pos] = (unsigned short)n;
        }
    } else if (blk < 2 * BB) {
        int b = blk - BB;
        if (tid < LL) hist[tid] = 0;
        __syncthreads();
        for (int m = tid; m < MM; m += 256) atomicAdd(&hist[glab[b * MM + m]], 1);
        __syncthreads();
        if (tid < LL) {
            int s = 0;
            for (int j = 0; j < tid; ++j) s += hist[j];
            cur[tid] = s; gstart[b * LL + tid] = s; gcnt[b * LL + tid] = hist[tid];
        }
        __syncthreads();
        for (int m = tid; m < MM; m += 256) {
            int l = glab[b * MM + m];
            int pos = atomicAdd(&cur[l], 1);
            gidx[b * MM + pos] = (unsigned short)m;
        }
    } else {
        int i = (blk - 2 * BB) * 256 + tid;
        if (i < BB * MM) counts[i] = 0;
    }

    __threadfence();
    gg.sync();

    // ---- Phase 1: one wave per GT bucket slot (grid-stride over 4800 slots).
    //      Exact top-k(v,idx) top-4, gmax, packed GT record in bucket order.
    {
        const int lane = tid & 63;
        const int wv = (blk << 2) + (tid >> 6);
        const int nw = GRID << 2;
        float* topv = out + 38400;
        int*   topi = (int*)(out + 57600);
        float4* gtb = (float4*)out;
        for (int task = wv; task < BB * MM; task += nw) {
            int tt = __builtin_amdgcn_readfirstlane(task);
            int b = tt / MM, g = tt - b * MM;
            int m = gidx[b * MM + g];
            int bm = b * MM + m;
            Box gt = to_xyxy(gbox[bm]);
            int l = glab[bm];
            int s = pstart[b * LL + l], c = pcnt[b * LL + l];

            const u64 init = ((u64)f32_to_ordered(-1.0f) << 32);
            u64 t[4] = {init, init, init, init};
            for (int i = lane; i < c; i += 64) {   // c ~ 37, usually a single pass
                int n = pidx[b * NN + s + i];
                Box pb = to_xyxy(props[(size_t)b * NN + n]);
                float iou = pair_iou(gt, pb);      // all bucket entries match -> v = iou
                u64 key = ((u64)f32_to_ordered(iou) << 32) |
                          (u64)(0xFFFFFFFFu - (unsigned)n);
                topins(t, key);
            }
            wave_merge_top4(t);

            if (lane == 0) {
                #pragma unroll
                for (int j = 0; j < KK; ++j) {
                    topv[bm * KK + j] = ordered_to_f32((unsigned)(t[j] >> 32));
                    topi[bm * KK + j] = (int)(0xFFFFFFFFu - (unsigned)t[j]);
                }
                float gm = ordered_to_f32((unsigned)(t[0] >> 32));
                int gpos = b * MM + g;
                gtb[gpos * 2 + 0] = make_float4(gt.x1, gt.y1, gt.x2, gt.y2);
                gtb[gpos * 2 + 1] = make_float4(gt.area, gm, __int_as_float(m), 0.0f);
            }
        }
    }

    __threadfence();
    gg.sync();

    // ---- Phase 2: one thread per proposal; scan GT bucket of its label (~3.75
    //      rows): best_gt via u64 key (min-m tie-break), lq via exact iou==gmax.
    {
        const int gtid = blk * 256 + tid;
        const int gsz = GRID * 256;
        const float4* gtb = (const float4*)out;
        for (int i = gtid; i < BB * NN; i += gsz) {
            int b = i / NN;
            float4 pr = props[i];
            int lbl = pinds[i];
            Box pb = to_xyxy(pr);
            int s = gstart[b * LL + lbl], c = gcnt[b * LL + lbl];

            u64 key = 0;
            bool lq = false;
            for (int j = 0; j < c; ++j) {
                int idx = (b * MM + s + j) * 2;
                float4 q0 = gtb[idx], q1 = gtb[idx + 1];
                Box a; a.x1 = q0.x; a.y1 = q0.y; a.x2 = q0.z; a.y2 = q0.w; a.area = q1.x;
                float iou = pair_iou(a, pb);
                int m = __float_as_int(q1.z);
                u64 k = ((u64)f32_to_ordered(iou) << 32) |
                        (u64)(0xFFFFFFFFu - (unsigned)m);
                key = umax64(key, k);
                lq = lq || (iou == q1.y);
            }
            if (c > 0) {  // valid_prop; all scanned pairs match so best v >= 0
                float v = ordered_to_f32((unsigned)(key >> 32));
                int bm = (int)(0xFFFFFFFFu - (unsigned)key);
                if ((v >= IOU_THRESH) || lq) atomicAdd(&counts[b * MM + bm], 1);
            }
        }
    }

    __threadfence();
    gg.sync();

    // ---- Phase 3: epilogue. Overlapping slots are read-before-write within the
    //      same thread; GT-record region (chunks 0-1) is dead after phase 2.
    {
        const int gtid = blk * 256 + tid;
        const int gsz = GRID * 256;
        for (int i = gtid; i < BB * MM; i += gsz) {
            int m = i % MM;
            int take = min(counts[i], KK);
            float4 tv = ((const float4*)(out + 38400))[i];
            int4   ti = ((const int4*)(out + 57600))[i];
            float4 rows, cols, valid, sel;
            rows.x = (0 < take) ? (float)ti.x : -1.0f;
            rows.y = (1 < take) ? (float)ti.y : -1.0f;
            rows.z = (2 < take) ? (float)ti.z : -1.0f;
            rows.w = (3 < take) ? (float)ti.w : -1.0f;
            cols.x = (0 < take) ? (float)m : -1.0f;
            cols.y = (1 < take) ? (float)m : -1.0f;
            cols.z = (2 < take) ? (float)m : -1.0f;
            cols.w = (3 < take) ? (float)m : -1.0f;
            valid.x = (0 < take) ? 1.0f : 0.0f;
            valid.y = (1 < take) ? 1.0f : 0.0f;
            valid.z = (2 < take) ? 1.0f : 0.0f;
            valid.w = (3 < take) ? 1.0f : 0.0f;
            sel.x = (0 < take) ? tv.x : 0.0f;
            sel.y = (1 < take) ? tv.y : 0.0f;
            sel.z = (2 < take) ? tv.z : 0.0f;
            sel.w = (3 < take) ? tv.w : 0.0f;
            float4* o = (float4*)out;
            const int CH4 = BB * MM;  // 4800 float4s per chunk
            o[0 * CH4 + i] = rows;
            o[1 * CH4 + i] = cols;
            o[2 * CH4 + i] = valid;
            o[3 * CH4 + i] = sel;
        }
    }
}

// ===========================================================================
// Fallback path: the previously-verified 4-kernel pipeline (used only if the
// cooperative launch is rejected by the runtime / graph capture).
// ===========================================================================
__global__ __launch_bounds__(256) void kBin(const int* __restrict__ pinds,
                                            const int* __restrict__ glab,
                                            unsigned short* __restrict__ pidx,
                                            int* __restrict__ pstart,
                                            int* __restrict__ pcnt,
                                            unsigned short* __restrict__ gidx,
                                            int* __restrict__ gstart,
                                            int* __restrict__ gcnt,
                                            int* __restrict__ counts) {
    int b = blockIdx.x;
    int tid = threadIdx.x;
    __shared__ int hist[LL], cur[LL], gh[LL], gcur[LL];
    if (tid < LL) { hist[tid] = 0; gh[tid] = 0; }
    __syncthreads();
    for (int n = tid; n < NN; n += 256) atomicAdd(&hist[pinds[b * NN + n]], 1);
    for (int m = tid; m < MM; m += 256) atomicAdd(&gh[glab[b * MM + m]], 1);
    __syncthreads();
    if (tid < LL) {
        int s = 0;
        for (int j = 0; j < tid; ++j) s += hist[j];
        cur[tid] = s; pstart[b * LL + tid] = s; pcnt[b * LL + tid] = hist[tid];
        int t = 0;
        for (int j = 0; j < tid; ++j) t += gh[j];
        gcur[tid] = t; gstart[b * LL + tid] = t; gcnt[b * LL + tid] = gh[tid];
    }
    __syncthreads();
    for (int n = tid; n < NN; n += 256) {
        int l = pinds[b * NN + n];
        int pos = atomicAdd(&cur[l], 1);
        pidx[b * NN + pos] = (unsigned short)n;
    }
    for (int m = tid; m < MM; m += 256) {
        int l = glab[b * MM + m];
        int pos = atomicAdd(&gcur[l], 1);
        gidx[b * MM + pos] = (unsigned short)m;
    }
    for (int i = tid; i < MM; i += 256) counts[b * MM + i] = 0;
}

__global__ __launch_bounds__(256) void kTop(const float4* __restrict__ props,
                                            const int*    __restrict__ glab,
                                            const float4* __restrict__ gbox,
                                            const unsigned short* __restrict__ pidx,
                                            const int* __restrict__ pstart,
                                            const int* __restrict__ pcnt,
                                            const unsigned short* __restrict__ gidx,
                                            float* out) {
    int b = blockIdx.y;
    int wv = __builtin_amdgcn_readfirstlane((int)(threadIdx.x >> 6));
    int lane = threadIdx.x & 63;
    int g = blockIdx.x * 4 + wv;
    int m = gidx[b * MM + g];
    int bm = b * MM + m;
    Box gt = to_xyxy(gbox[bm]);
    int l = glab[bm];
    int s = pstart[b * LL + l], c = pcnt[b * LL + l];

    const u64 init = ((u64)f32_to_ordered(-1.0f) << 32);
    u64 t[4] = {init, init, init, init};
    for (int i = lane; i < c; i += 64) {
        int n = pidx[b * NN + s + i];
        Box pb = to_xyxy(props[(size_t)b * NN + n]);
        float iou = pair_iou(gt, pb);
        u64 key = ((u64)f32_to_ordered(iou) << 32) |
                  (u64)(0xFFFFFFFFu - (unsigned)n);
        topins(t, key);
    }
    wave_merge_top4(t);

    if (lane == 0) {
        float* topv = out + 38400;
        int*   topi = (int*)(out + 57600);
        #pragma unroll
        for (int j = 0; j < KK; ++j) {
            topv[bm * KK + j] = ordered_to_f32((unsigned)(t[j] >> 32));
            topi[bm * KK + j] = (int)(0xFFFFFFFFu - (unsigned)t[j]);
        }
        float gm = ordered_to_f32((unsigned)(t[0] >> 32));
        float4* gtb = (float4*)out;
        int gpos = b * MM + g;
        gtb[gpos * 2 + 0] = make_float4(gt.x1, gt.y1, gt.x2, gt.y2);
        gtb[gpos * 2 + 1] = make_float4(gt.area, gm, __int_as_float(m), 0.0f);
    }
}

__global__ __launch_bounds__(256) void kAsn(const float4* __restrict__ props,
                                            const int*    __restrict__ pinds,
                                            const int* __restrict__ gstart,
                                            const int* __restrict__ gcnt,
                                            const float* __restrict__ out,
                                            int* __restrict__ counts) {
    int b = blockIdx.y;
    int n = blockIdx.x * 256 + threadIdx.x;
    if (n >= NN) return;
    float4 pr = props[(size_t)b * NN + n];
    int lbl = pinds[(size_t)b * NN + n];
    Box pb = to_xyxy(pr);
    int s = gstart[b * LL + lbl], c = gcnt[b * LL + lbl];
    const float4* gtb = (const float4*)out;

    u64 key = 0;
    bool lq = false;
    for (int j = 0; j < c; ++j) {
        int idx = (b * MM + s + j) * 2;
        float4 q0 = gtb[idx], q1 = gtb[idx + 1];
        Box a; a.x1 = q0.x; a.y1 = q0.y; a.x2 = q0.z; a.y2 = q0.w; a.area = q1.x;
        float iou = pair_iou(a, pb);
        int m = __float_as_int(q1.z);
        u64 k = ((u64)f32_to_ordered(iou) << 32) |
                (u64)(0xFFFFFFFFu - (unsigned)m);
        key = umax64(key, k);
        lq = lq || (iou == q1.y);
    }
    if (c > 0) {
        float v = ordered_to_f32((unsigned)(key >> 32));
        int bm = (int)(0xFFFFFFFFu - (unsigned)key);
        if ((v >= IOU_THRESH) || lq) atomicAdd(&counts[b * MM + bm], 1);
    }
}

__global__ __launch_bounds__(256) void kC(const int* __restrict__ counts,
                                          float* out) {
    int i = blockIdx.x * 256 + threadIdx.x;
    if (i >= BB * MM) return;
    int m = i % MM;
    int take = min(counts[i], KK);
    float4 tv = ((const float4*)(out + 38400))[i];
    int4   ti = ((const int4*)(out + 57600))[i];
    float4 rows, cols, valid, sel;
    rows.x = (0 < take) ? (float)ti.x : -1.0f;
    rows.y = (1 < take) ? (float)ti.y : -1.0f;
    rows.z = (2 < take) ? (float)ti.z : -1.0f;
    rows.w = (3 < take) ? (float)ti.w : -1.0f;
    cols.x = (0 < take) ? (float)m : -1.0f;
    cols.y = (1 < take) ? (float)m : -1.0f;
    cols.z = (2 < take) ? (float)m : -1.0f;
    cols.w = (3 < take) ? (float)m : -1.0f;
    valid.x = (0 < take) ? 1.0f : 0.0f;
    valid.y = (1 < take) ? 1.0f : 0.0f;
    valid.z = (2 < take) ? 1.0f : 0.0f;
    valid.w = (3 < take) ? 1.0f : 0.0f;
    sel.x = (0 < take) ? tv.x : 0.0f;
    sel.y = (1 < take) ? tv.y : 0.0f;
    sel.z = (2 < take) ? tv.z : 0.0f;
    sel.w = (3 < take) ? tv.w : 0.0f;
    float4* o = (float4*)out;
    const int CH4 = BB * MM;
    o[0 * CH4 + i] = rows;
    o[1 * CH4 + i] = cols;
    o[2 * CH4 + i] = valid;
    o[3 * CH4 + i] = sel;
}

extern "C" void kernel_launch(void* const* d_in, const int* in_sizes, int n_in,
                              void* d_out, int out_size, void* d_ws, size_t ws_size,
                              hipStream_t stream) {
    // inputs: 0 pred_logits_match (unused), 1 pred_boxes (unused),
    //         2 init_reference (proposals), 3 prompt_inds, 4 gt_labels,
    //         5 gt_boxes, 6 max_k (==4, hardcoded)
    const float4* props = (const float4*)d_in[2];
    const int*    pinds = (const int*)d_in[3];
    const int*    glab  = (const int*)d_in[4];
    const float4* gbox  = (const float4*)d_in[5];
    float* out = (float*)d_out;

    // ws layout (145.3 KB total):
    char* w = (char*)d_ws;
    int*   counts = (int*)w;                 w += BB * MM * sizeof(int);      // 19200
    int*   pstart = (int*)w;                 w += BB * LL * sizeof(int);      //  5120
    int*   pcnt   = (int*)w;                 w += BB * LL * sizeof(int);      //  5120
    int*   gstart = (int*)w;                 w += BB * LL * sizeof(int);      //  5120
    int*   gcnt   = (int*)w;                 w += BB * LL * sizeof(int);      //  5120
    unsigned short* pidx = (unsigned short*)w; w += BB * NN * sizeof(short);  // 96000
    unsigned short* gidx = (unsigned short*)w;                                //  9600

    void* args[] = { (void*)&props, (void*)&pinds, (void*)&glab, (void*)&gbox,
                     (void*)&out, (void*)&counts, (void*)&pstart, (void*)&pcnt,
                     (void*)&gstart, (void*)&gcnt, (void*)&pidx, (void*)&gidx };
    hipError_t err = hipLaunchCooperativeKernel((void*)kAll, dim3(GRID), dim3(256),
                                                args, 0u, stream);
    if (err != hipSuccess) {
        // Fallback: verified 4-kernel pipeline.
        kBin<<<BB, 256, 0, stream>>>(pinds, glab, pidx, pstart, pcnt,
                                     gidx, gstart, gcnt, counts);
        dim3 gT(MM / 4, BB);
        kTop<<<gT, 256, 0, stream>>>(props, glab, gbox, pidx, pstart, pcnt, gidx, out);
        dim3 gA((NN + 255) / 256, BB);
        kAsn<<<gA, 256, 0, stream>>>(props, pinds, gstart, gcnt, out, counts);
        kC<<<(BB * MM + 255) / 256, 256, 0, stream>>>(counts, out);
    }
}

// Round 2
// 263.355 us; speedup vs baseline: 1.4857x; 1.4857x over previous
//
#include <hip/hip_runtime.h>

// Problem constants (fixed by setup_inputs): B=16, N=3000, M=300, L=80, K=4
#define BB 16
#define NN 3000
#define MM 300
#define LL 80
#define KK 4
#define IOU_THRESH 0.6f
#define GRID 512   // kMain blocks; VGPR=28/LDS=0 -> all 512 co-resident (2/CU) for the sw barrier

typedef unsigned long long u64;

struct Box { float x1, y1, x2, y2, area; };

__device__ __forceinline__ Box to_xyxy(float4 b) {
#pragma clang fp contract(off)
    Box r;
    r.x1 = b.x - 0.5f * b.z;
    r.y1 = b.y - 0.5f * b.w;
    r.x2 = b.x + 0.5f * b.z;
    r.y2 = b.y + 0.5f * b.w;
    r.area = (r.x2 - r.x1) * (r.y2 - r.y1);
    return r;
}

// Must be bitwise-identical between top phase and asn phase (iou == gmax equality depends on it).
__device__ __forceinline__ float pair_iou(Box a, Box b) {
#pragma clang fp contract(off)
    float ltx = fmaxf(a.x1, b.x1);
    float lty = fmaxf(a.y1, b.y1);
    float rbx = fminf(a.x2, b.x2);
    float rby = fminf(a.y2, b.y2);
    float wx = fmaxf(rbx - ltx, 0.0f);
    float wy = fmaxf(rby - lty, 0.0f);
    float inter = wx * wy;
    float uni = a.area + b.area - inter;
    return inter / fmaxf(uni, 1e-9f);
}

// monotonic float <-> u32 (order-preserving bijection, finite values)
__device__ __forceinline__ unsigned int f32_to_ordered(float f) {
    unsigned int u = __float_as_uint(f);
    return (u & 0x80000000u) ? ~u : (u | 0x80000000u);
}
__device__ __forceinline__ float ordered_to_f32(unsigned int u) {
    unsigned int b = (u & 0x80000000u) ? (u & 0x7FFFFFFFu) : ~u;
    return __uint_as_float(b);
}

__device__ __forceinline__ u64 umax64(u64 a, u64 b) { return a > b ? a : b; }
__device__ __forceinline__ u64 umin64(u64 a, u64 b) { return a < b ? a : b; }

__device__ __forceinline__ u64 shfl_xor_u64(u64 v, int mask) {
    int lo = __shfl_xor((int)(unsigned)v, mask, 64);
    int hi = __shfl_xor((int)(unsigned)(v >> 32), mask, 64);
    return ((u64)(unsigned)hi << 32) | (u64)(unsigned)lo;
}

// branchless insert of k into sorted-desc 4-list
__device__ __forceinline__ void topins(u64 t[4], u64 k) {
    u64 c0 = umin64(t[0], k);
    t[0] = umax64(t[0], k);
    u64 c1 = umin64(t[1], c0);
    t[1] = umax64(t[1], c0);
    u64 c2 = umin64(t[2], c1);
    t[2] = umax64(t[2], c1);
    t[3] = umax64(t[3], c2);
}

// butterfly: top-4 of the union of all 64 lanes' sorted-desc 4-lists (all lanes get result)
__device__ __forceinline__ void wave_merge_top4(u64 t[4]) {
    #pragma unroll
    for (int s = 1; s < 64; s <<= 1) {
        u64 b0 = shfl_xor_u64(t[0], s);
        u64 b1 = shfl_xor_u64(t[1], s);
        u64 b2 = shfl_xor_u64(t[2], s);
        u64 b3 = shfl_xor_u64(t[3], s);
        u64 a0 = t[0], a1 = t[1], a2 = t[2], a3 = t[3];
        t[0] = umax64(a0, b0);
        t[1] = umax64(umin64(a0, b0), umax64(a1, b1));
        t[2] = umax64(umax64(a2, b2), umax64(umin64(a0, b1), umin64(a1, b0)));
        t[3] = umax64(umax64(a3, b3),
               umax64(umin64(a0, b2), umax64(umin64(a1, b1), umin64(a2, b0))));
    }
}

// ---------------------------------------------------------------------------
// Fast sense-reversing grid barrier (agent-scope atomics in L2, short s_sleep
// polling). Replaces cg::grid_group::sync(), which measured ~90us per sync
// (system-scope + long-backoff spin). Requires all GRID blocks co-resident.
// Race-freedom: gen is read BEFORE arrival (no release possible until this
// block arrives, so g is the current generation); releaser resets cnt before
// the release-store to gen, so next-barrier arrivals (which first acquire gen)
// see cnt==0.
// ---------------------------------------------------------------------------
__device__ __forceinline__ void grid_barrier(unsigned* cnt, unsigned* gen) {
    __syncthreads();
    if (threadIdx.x == 0) {
        __threadfence();  // publish this block's prior writes (device scope)
        unsigned g = __hip_atomic_load(gen, __ATOMIC_ACQUIRE, __HIP_MEMORY_SCOPE_AGENT);
        unsigned a = __hip_atomic_fetch_add(cnt, 1u, __ATOMIC_ACQ_REL, __HIP_MEMORY_SCOPE_AGENT);
        if (a == GRID - 1) {
            __hip_atomic_store(cnt, 0u, __ATOMIC_RELAXED, __HIP_MEMORY_SCOPE_AGENT);
            __hip_atomic_store(gen, g + 1u, __ATOMIC_RELEASE, __HIP_MEMORY_SCOPE_AGENT);
        } else {
            while (__hip_atomic_load(gen, __ATOMIC_ACQUIRE, __HIP_MEMORY_SCOPE_AGENT) == g) {
                __builtin_amdgcn_s_sleep(1);
            }
        }
        __threadfence();  // acquire side: order subsequent reads after release
    }
    __syncthreads();
}

// ---------------------------------------------------------------------------
// kPrep: 32 blocks. Blocks 0..15 bin proposals for batch b=blk; blocks 16..31
// bin GT rows for batch b=blk-16. All blocks grid-stride-zero counts; block 0
// zeroes the barrier state. Bucket order is nondeterministic (LDS atomic
// cursors) but downstream results are order-invariant (u64 key max / OR / adds).
// ---------------------------------------------------------------------------
__global__ __launch_bounds__(256) void kPrep(const int* __restrict__ pinds,
                                             const int* __restrict__ glab,
                                             unsigned short* __restrict__ pidx,
                                             int* __restrict__ pstart,
                                             int* __restrict__ pcnt,
                                             unsigned short* __restrict__ gidx,
                                             int* __restrict__ gstart,
                                             int* __restrict__ gcnt,
                                             int* __restrict__ counts,
                                             unsigned* __restrict__ bar) {
    int blk = blockIdx.x;
    int tid = threadIdx.x;
    __shared__ int hist[LL], cur[LL];

    if (blk == 0 && tid == 0) { bar[0] = 0u; bar[1] = 0u; }

    for (int i = blk * 256 + tid; i < BB * MM; i += 32 * 256) counts[i] = 0;

    if (blk < BB) {
        int b = blk;
        if (tid < LL) hist[tid] = 0;
        __syncthreads();
        for (int n = tid; n < NN; n += 256) atomicAdd(&hist[pinds[b * NN + n]], 1);
        __syncthreads();
        if (tid < LL) {
            int s = 0;
            for (int j = 0; j < tid; ++j) s += hist[j];
            cur[tid] = s; pstart[b * LL + tid] = s; pcnt[b * LL + tid] = hist[tid];
        }
        __syncthreads();
        for (int n = tid; n < NN; n += 256) {
            int l = pinds[b * NN + n];
            int pos = atomicAdd(&cur[l], 1);
            pidx[b * NN + pos] = (unsigned short)n;
        }
    } else {
        int b = blk - BB;
        if (tid < LL) hist[tid] = 0;
        __syncthreads();
        for (int m = tid; m < MM; m += 256) atomicAdd(&hist[glab[b * MM + m]], 1);
        __syncthreads();
        if (tid < LL) {
            int s = 0;
            for (int j = 0; j < tid; ++j) s += hist[j];
            cur[tid] = s; gstart[b * LL + tid] = s; gcnt[b * LL + tid] = hist[tid];
        }
        __syncthreads();
        for (int m = tid; m < MM; m += 256) {
            int l = glab[b * MM + m];
            int pos = atomicAdd(&cur[l], 1);
            gidx[b * MM + pos] = (unsigned short)m;
        }
    }
}

// ---------------------------------------------------------------------------
// kMain: 512 blocks. top -> bar -> asn -> bar -> epilogue. Phase bodies are
// verbatim from the verified 4-kernel pipeline.
// d_out layout: floats [0,38400) GT records | [38400,57600) topv | [57600,76800) topi
// ---------------------------------------------------------------------------
__global__ __launch_bounds__(256, 2) void kMain(
    const float4* __restrict__ props, const int* __restrict__ pinds,
    const int* __restrict__ glab, const float4* __restrict__ gbox,
    float* __restrict__ out, int* __restrict__ counts,
    const int* __restrict__ pstart, const int* __restrict__ pcnt,
    const int* __restrict__ gstart, const int* __restrict__ gcnt,
    const unsigned short* __restrict__ pidx, const unsigned short* __restrict__ gidx,
    unsigned* __restrict__ bar)
{
    const int tid = threadIdx.x;
    const int blk = blockIdx.x;

    // ---- Phase 1: one wave per GT bucket slot (grid-stride over 4800 slots).
    //      Exact top-k(v,idx) top-4, gmax, packed GT record in bucket order.
    {
        const int lane = tid & 63;
        const int wv = (blk << 2) + (tid >> 6);
        const int nw = GRID << 2;
        float* topv = out + 38400;
        int*   topi = (int*)(out + 57600);
        float4* gtb = (float4*)out;
        for (int task = wv; task < BB * MM; task += nw) {
            int tt = __builtin_amdgcn_readfirstlane(task);
            int b = tt / MM, g = tt - b * MM;
            int m = gidx[b * MM + g];
            int bm = b * MM + m;
            Box gt = to_xyxy(gbox[bm]);
            int l = glab[bm];
            int s = pstart[b * LL + l], c = pcnt[b * LL + l];

            const u64 init = ((u64)f32_to_ordered(-1.0f) << 32);
            u64 t[4] = {init, init, init, init};
            for (int i = lane; i < c; i += 64) {   // c ~ 37, usually a single pass
                int n = pidx[b * NN + s + i];
                Box pb = to_xyxy(props[(size_t)b * NN + n]);
                float iou = pair_iou(gt, pb);      // all bucket entries match -> v = iou
                u64 key = ((u64)f32_to_ordered(iou) << 32) |
                          (u64)(0xFFFFFFFFu - (unsigned)n);
                topins(t, key);
            }
            wave_merge_top4(t);

            if (lane == 0) {
                #pragma unroll
                for (int j = 0; j < KK; ++j) {
                    topv[bm * KK + j] = ordered_to_f32((unsigned)(t[j] >> 32));
                    topi[bm * KK + j] = (int)(0xFFFFFFFFu - (unsigned)t[j]);
                }
                float gm = ordered_to_f32((unsigned)(t[0] >> 32));
                int gpos = b * MM + g;
                gtb[gpos * 2 + 0] = make_float4(gt.x1, gt.y1, gt.x2, gt.y2);
                gtb[gpos * 2 + 1] = make_float4(gt.area, gm, __int_as_float(m), 0.0f);
            }
        }
    }

    grid_barrier(bar, bar + 1);

    // ---- Phase 2: one thread per proposal; scan GT bucket of its label (~3.75
    //      rows): best_gt via u64 key (min-m tie-break), lq via exact iou==gmax.
    {
        const int gtid = blk * 256 + tid;
        const int gsz = GRID * 256;
        const float4* gtb = (const float4*)out;
        for (int i = gtid; i < BB * NN; i += gsz) {
            int b = i / NN;
            float4 pr = props[i];
            int lbl = pinds[i];
            Box pb = to_xyxy(pr);
            int s = gstart[b * LL + lbl], c = gcnt[b * LL + lbl];

            u64 key = 0;
            bool lq = false;
            for (int j = 0; j < c; ++j) {
                int idx = (b * MM + s + j) * 2;
                float4 q0 = gtb[idx], q1 = gtb[idx + 1];
                Box a; a.x1 = q0.x; a.y1 = q0.y; a.x2 = q0.z; a.y2 = q0.w; a.area = q1.x;
                float iou = pair_iou(a, pb);
                int m = __float_as_int(q1.z);
                u64 k = ((u64)f32_to_ordered(iou) << 32) |
                        (u64)(0xFFFFFFFFu - (unsigned)m);
                key = umax64(key, k);
                lq = lq || (iou == q1.y);
            }
            if (c > 0) {  // valid_prop; all scanned pairs match so best v >= 0
                float v = ordered_to_f32((unsigned)(key >> 32));
                int bm = (int)(0xFFFFFFFFu - (unsigned)key);
                if ((v >= IOU_THRESH) || lq) atomicAdd(&counts[b * MM + bm], 1);
            }
        }
    }

    grid_barrier(bar, bar + 1);

    // ---- Phase 3: epilogue. Overlapping slots (chunk2==topv, chunk3==topi
    //      regions) are read-before-write within the same thread; GT-record
    //      region (chunks 0-1) is dead after phase 2.
    {
        const int gtid = blk * 256 + tid;
        for (int i = gtid; i < BB * MM; i += GRID * 256) {
            int m = i % MM;
            int take = min(counts[i], KK);
            float4 tv = ((const float4*)(out + 38400))[i];
            int4   ti = ((const int4*)(out + 57600))[i];
            float4 rows, cols, valid, sel;
            rows.x = (0 < take) ? (float)ti.x : -1.0f;
            rows.y = (1 < take) ? (float)ti.y : -1.0f;
            rows.z = (2 < take) ? (float)ti.z : -1.0f;
            rows.w = (3 < take) ? (float)ti.w : -1.0f;
            cols.x = (0 < take) ? (float)m : -1.0f;
            cols.y = (1 < take) ? (float)m : -1.0f;
            cols.z = (2 < take) ? (float)m : -1.0f;
            cols.w = (3 < take) ? (float)m : -1.0f;
            valid.x = (0 < take) ? 1.0f : 0.0f;
            valid.y = (1 < take) ? 1.0f : 0.0f;
            valid.z = (2 < take) ? 1.0f : 0.0f;
            valid.w = (3 < take) ? 1.0f : 0.0f;
            sel.x = (0 < take) ? tv.x : 0.0f;
            sel.y = (1 < take) ? tv.y : 0.0f;
            sel.z = (2 < take) ? tv.z : 0.0f;
            sel.w = (3 < take) ? tv.w : 0.0f;
            float4* o = (float4*)out;
            const int CH4 = BB * MM;  // 4800 float4s per chunk
            o[0 * CH4 + i] = rows;
            o[1 * CH4 + i] = cols;
            o[2 * CH4 + i] = valid;
            o[3 * CH4 + i] = sel;
        }
    }
}

extern "C" void kernel_launch(void* const* d_in, const int* in_sizes, int n_in,
                              void* d_out, int out_size, void* d_ws, size_t ws_size,
                              hipStream_t stream) {
    // inputs: 0 pred_logits_match (unused), 1 pred_boxes (unused),
    //         2 init_reference (proposals), 3 prompt_inds, 4 gt_labels,
    //         5 gt_boxes, 6 max_k (==4, hardcoded)
    const float4* props = (const float4*)d_in[2];
    const int*    pinds = (const int*)d_in[3];
    const int*    glab  = (const int*)d_in[4];
    const float4* gbox  = (const float4*)d_in[5];
    float* out = (float*)d_out;

    // ws layout (145.3 KB + 8B barrier):
    char* w = (char*)d_ws;
    int*   counts = (int*)w;                 w += BB * MM * sizeof(int);      // 19200
    int*   pstart = (int*)w;                 w += BB * LL * sizeof(int);      //  5120
    int*   pcnt   = (int*)w;                 w += BB * LL * sizeof(int);      //  5120
    int*   gstart = (int*)w;                 w += BB * LL * sizeof(int);      //  5120
    int*   gcnt   = (int*)w;                 w += BB * LL * sizeof(int);      //  5120
    unsigned short* pidx = (unsigned short*)w; w += BB * NN * sizeof(short);  // 96000
    unsigned short* gidx = (unsigned short*)w; w += BB * MM * sizeof(short);  //  9600
    unsigned* bar = (unsigned*)w;            // 8 bytes: {cnt, gen}

    kPrep<<<32, 256, 0, stream>>>(pinds, glab, pidx, pstart, pcnt,
                                  gidx, gstart, gcnt, counts, bar);
    kMain<<<GRID, 256, 0, stream>>>(props, pinds, glab, gbox, out, counts,
                                    pstart, pcnt, gstart, gcnt, pidx, gidx, bar);
}

// Round 3
// 81.059 us; speedup vs baseline: 4.8269x; 3.2489x over previous
//
#include <hip/hip_runtime.h>

// Problem constants (fixed by setup_inputs): B=16, N=3000, M=300, L=80, K=4
#define BB 16
#define NN 3000
#define MM 300
#define LL 80
#define KK 4
#define IOU_THRESH 0.6f

typedef unsigned long long u64;

struct Box { float x1, y1, x2, y2, area; };

__device__ __forceinline__ Box to_xyxy(float4 b) {
#pragma clang fp contract(off)
    Box r;
    r.x1 = b.x - 0.5f * b.z;
    r.y1 = b.y - 0.5f * b.w;
    r.x2 = b.x + 0.5f * b.z;
    r.y2 = b.y + 0.5f * b.w;
    r.area = (r.x2 - r.x1) * (r.y2 - r.y1);
    return r;
}

// Same inlined function used in both the top phase and the asn phase (the
// lq test relies on bitwise-identical iou; same argument order everywhere).
__device__ __forceinline__ float pair_iou(Box a, Box b) {
#pragma clang fp contract(off)
    float ltx = fmaxf(a.x1, b.x1);
    float lty = fmaxf(a.y1, b.y1);
    float rbx = fminf(a.x2, b.x2);
    float rby = fminf(a.y2, b.y2);
    float wx = fmaxf(rbx - ltx, 0.0f);
    float wy = fmaxf(rby - lty, 0.0f);
    float inter = wx * wy;
    float uni = a.area + b.area - inter;
    return inter / fmaxf(uni, 1e-9f);
}

// monotonic float <-> u32 (order-preserving bijection, finite values)
__device__ __forceinline__ unsigned int f32_to_ordered(float f) {
    unsigned int u = __float_as_uint(f);
    return (u & 0x80000000u) ? ~u : (u | 0x80000000u);
}
__device__ __forceinline__ float ordered_to_f32(unsigned int u) {
    unsigned int b = (u & 0x80000000u) ? (u & 0x7FFFFFFFu) : ~u;
    return __uint_as_float(b);
}

__device__ __forceinline__ u64 umax64(u64 a, u64 b) { return a > b ? a : b; }
__device__ __forceinline__ u64 umin64(u64 a, u64 b) { return a < b ? a : b; }

__device__ __forceinline__ u64 shfl_xor_u64(u64 v, int mask) {
    int lo = __shfl_xor((int)(unsigned)v, mask, 64);
    int hi = __shfl_xor((int)(unsigned)(v >> 32), mask, 64);
    return ((u64)(unsigned)hi << 32) | (u64)(unsigned)lo;
}

// branchless insert of k into sorted-desc 4-list
__device__ __forceinline__ void topins(u64 t[4], u64 k) {
    u64 c0 = umin64(t[0], k);
    t[0] = umax64(t[0], k);
    u64 c1 = umin64(t[1], c0);
    t[1] = umax64(t[1], c0);
    u64 c2 = umin64(t[2], c1);
    t[2] = umax64(t[2], c1);
    t[3] = umax64(t[3], c2);
}

// butterfly: top-4 of the union of all 64 lanes' sorted-desc 4-lists (all lanes get result)
__device__ __forceinline__ void wave_merge_top4(u64 t[4]) {
    #pragma unroll
    for (int s = 1; s < 64; s <<= 1) {
        u64 b0 = shfl_xor_u64(t[0], s);
        u64 b1 = shfl_xor_u64(t[1], s);
        u64 b2 = shfl_xor_u64(t[2], s);
        u64 b3 = shfl_xor_u64(t[3], s);
        u64 a0 = t[0], a1 = t[1], a2 = t[2], a3 = t[3];
        t[0] = umax64(a0, b0);
        t[1] = umax64(umin64(a0, b0), umax64(a1, b1));
        t[2] = umax64(umax64(a2, b2), umax64(umin64(a0, b1), umin64(a1, b0)));
        t[3] = umax64(umax64(a3, b3),
               umax64(umin64(a0, b2), umax64(umin64(a1, b1), umin64(a2, b0))));
    }
}

// ===========================================================================
// kFused: ONE block per (label, batch) bucket — grid (80, 16), 256 threads.
// The whole pipeline's dataflow is confined to a (b,l) bucket:
//   - a GT row's top-4 / gmax needs only proposals of its own label
//   - a proposal's best_gt / lq needs only GT rows (and gmax) of its label
//   - counts[m] only receives from proposals of m's label
//   - epilogue for m needs only bucket-local counts + top-4
// So bin -> top -> asn -> epilogue all run inside the block with
// __syncthreads(), eliminating the grid barriers (measured ~90us each on
// this chip: 512-way cross-XCD cacheline bouncing) AND the binning kernel.
// No workspace, no global intermediates; ~18.6 KB LDS.
// Every (b,m) output slot is written exactly once, by the unique bucket
// (glab[b][m], b). Bucket list order is nondeterministic (LDS atomic
// cursors) but all results are order-invariant (exact u64-key max with
// global-index tie-breaks).
// d_out layout: 4 chunks of BB*MM float4: rows | cols | valid | sel.
// ===========================================================================
__global__ __launch_bounds__(256) void kFused(
    const float4* __restrict__ props, const int* __restrict__ pinds,
    const int* __restrict__ glab, const float4* __restrict__ gbox,
    float* __restrict__ out)
{
    const int l = blockIdx.x;   // label
    const int b = blockIdx.y;   // batch
    const int tid = threadIdx.x;

    __shared__ unsigned short plist[NN];   // proposal indices of this bucket
    __shared__ unsigned short glist[MM];   // GT row indices of this bucket
    __shared__ float gmaxL[MM];            // per-bucket-row gmax
    __shared__ float tvL[MM * KK];         // per-bucket-row top-4 values
    __shared__ int   tiL[MM * KK];         // per-bucket-row top-4 indices
    __shared__ int   cntsL[MM];            // per-bucket-row pos counts
    __shared__ int pcur, gcur;

    if (tid == 0) { pcur = 0; gcur = 0; }
    for (int j = tid; j < MM; j += 256) cntsL[j] = 0;
    __syncthreads();

    // ---- bin: GT rows of this bucket (scan 300 labels)
    for (int m = tid; m < MM; m += 256) {
        if (glab[b * MM + m] == l) {
            int pos = atomicAdd(&gcur, 1);
            glist[pos] = (unsigned short)m;
        }
    }
    __syncthreads();
    const int cg_ = gcur;
    if (cg_ == 0) return;   // no GT rows with this label -> no outputs owned

    // ---- bin: proposals of this bucket (scan 3000 prompt_inds; 12 KB shared
    //      across the 80 blocks of this batch via L2)
    for (int n = tid; n < NN; n += 256) {
        if (pinds[b * NN + n] == l) {
            int pos = atomicAdd(&pcur, 1);
            plist[pos] = (unsigned short)n;
        }
    }
    __syncthreads();
    const int cp_ = pcur;

    // ---- top: one wave per bucket GT row. Exact lax.top_k top-4 (value desc,
    //      min-index tie-break) + gmax. Slots beyond cp_ stay at init and are
    //      always masked downstream (take <= counts <= cp_).
    {
        const int lane = tid & 63;
        const int wv = tid >> 6;
        for (int j = wv; j < cg_; j += 4) {
            int m = glist[j];
            Box gt = to_xyxy(gbox[b * MM + m]);
            const u64 init = ((u64)f32_to_ordered(-1.0f) << 32);
            u64 t[4] = {init, init, init, init};
            for (int i = lane; i < cp_; i += 64) {   // cp_ ~ 37, one pass
                int n = plist[i];
                Box pb = to_xyxy(props[(size_t)b * NN + n]);
                float iou = pair_iou(gt, pb);        // all bucket entries match
                u64 key = ((u64)f32_to_ordered(iou) << 32) |
                          (u64)(0xFFFFFFFFu - (unsigned)n);
                topins(t, key);
            }
            wave_merge_top4(t);
            if (lane == 0) {
                #pragma unroll
                for (int q = 0; q < KK; ++q) {
                    tvL[j * KK + q] = ordered_to_f32((unsigned)(t[q] >> 32));
                    tiL[j * KK + q] = (int)(0xFFFFFFFFu - (unsigned)t[q]);
                }
                gmaxL[j] = ordered_to_f32((unsigned)(t[0] >> 32));
            }
        }
    }
    __syncthreads();

    // ---- asn: one thread per bucket proposal. best_gt = argmax over bucket
    //      GT rows with min-global-m tie-break (matches argmax over all M rows:
    //      non-matching rows are -1 < any iou >= 0); lq via exact iou == gmax.
    for (int p = tid; p < cp_; p += 256) {
        int n = plist[p];
        Box pb = to_xyxy(props[(size_t)b * NN + n]);
        u64 key = 0;
        int bestj = 0;
        bool lq = false;
        for (int j = 0; j < cg_; ++j) {
            int m = glist[j];
            Box gt = to_xyxy(gbox[b * MM + m]);
            float iou = pair_iou(gt, pb);   // same arg order as top phase
            u64 k = ((u64)f32_to_ordered(iou) << 32) |
                    (u64)(0xFFFFFFFFu - (unsigned)m);
            if (k > key) { key = k; bestj = j; }  // distinct m -> never equal
            lq = lq || (iou == gmaxL[j]);
        }
        // cg_ >= 1 so key was set (iou >= 0 -> k >= 2^63 > 0)
        float v = ordered_to_f32((unsigned)(key >> 32));
        if ((v >= IOU_THRESH) || lq) atomicAdd(&cntsL[bestj], 1);
    }
    __syncthreads();

    // ---- epilogue: one thread per bucket GT row, write the 4 output chunks.
    for (int j = tid; j < cg_; j += 256) {
        int m = glist[j];
        int i = b * MM + m;
        int take = min(cntsL[j], KK);
        float4 rows, cols, valid, sel;
        rows.x = (0 < take) ? (float)tiL[j * KK + 0] : -1.0f;
        rows.y = (1 < take) ? (float)tiL[j * KK + 1] : -1.0f;
        rows.z = (2 < take) ? (float)tiL[j * KK + 2] : -1.0f;
        rows.w = (3 < take) ? (float)tiL[j * KK + 3] : -1.0f;
        cols.x = (0 < take) ? (float)m : -1.0f;
        cols.y = (1 < take) ? (float)m : -1.0f;
        cols.z = (2 < take) ? (float)m : -1.0f;
        cols.w = (3 < take) ? (float)m : -1.0f;
        valid.x = (0 < take) ? 1.0f : 0.0f;
        valid.y = (1 < take) ? 1.0f : 0.0f;
        valid.z = (2 < take) ? 1.0f : 0.0f;
        valid.w = (3 < take) ? 1.0f : 0.0f;
        sel.x = (0 < take) ? tvL[j * KK + 0] : 0.0f;
        sel.y = (1 < take) ? tvL[j * KK + 1] : 0.0f;
        sel.z = (2 < take) ? tvL[j * KK + 2] : 0.0f;
        sel.w = (3 < take) ? tvL[j * KK + 3] : 0.0f;
        float4* o = (float4*)out;
        const int CH4 = BB * MM;  // 4800 float4s per chunk
        o[0 * CH4 + i] = rows;
        o[1 * CH4 + i] = cols;
        o[2 * CH4 + i] = valid;
        o[3 * CH4 + i] = sel;
    }
}

extern "C" void kernel_launch(void* const* d_in, const int* in_sizes, int n_in,
                              void* d_out, int out_size, void* d_ws, size_t ws_size,
                              hipStream_t stream) {
    // inputs: 0 pred_logits_match (unused), 1 pred_boxes (unused),
    //         2 init_reference (proposals), 3 prompt_inds, 4 gt_labels,
    //         5 gt_boxes, 6 max_k (==4, hardcoded)
    const float4* props = (const float4*)d_in[2];
    const int*    pinds = (const int*)d_in[3];
    const int*    glab  = (const int*)d_in[4];
    const float4* gbox  = (const float4*)d_in[5];
    float* out = (float*)d_out;

    kFused<<<dim3(LL, BB), 256, 0, stream>>>(props, pinds, glab, gbox, out);
}